// Round 2
// baseline (591.990 us; speedup 1.0000x reference)
//
#include <hip/hip_runtime.h>

#define NQPTS 20000
#define NSUP  20000
#define NNB   30
#define NKP   15
#define KF    3840          // 15 * 256
#define EXTINV 20.0f        // 1 / 0.05

typedef __attribute__((ext_vector_type(4))) float f32x4;
typedef __attribute__((ext_vector_type(8))) short bf16x8;
typedef __attribute__((ext_vector_type(8))) unsigned short u16x8;

__device__ __forceinline__ unsigned short f2bf(float f){
  unsigned int u = __float_as_uint(f);
  u = (u + 0x7FFFu + ((u >> 16) & 1u)) >> 16;   // RNE
  return (unsigned short)u;
}

// ---------------------------------------------------------------------------
// weights f32 [3840][256]  ->  Bt bf16 [256][3840]  (transposed via LDS)
// ---------------------------------------------------------------------------
__global__ __launch_bounds__(256) void convert_wt(const float* __restrict__ W,
                                                  unsigned short* __restrict__ Bt){
  __shared__ unsigned short tile[64*130];
  const int kf0 = blockIdx.x * 128, o0 = blockIdx.y * 64;
  const int to = threadIdx.x & 63, tk = threadIdx.x >> 6;
  #pragma unroll
  for (int i = 0; i < 32; i++){
    int kf = i*4 + tk;                               // 0..127
    tile[to*130 + kf] = f2bf(W[(size_t)(kf0+kf)*256 + o0 + to]);
  }
  __syncthreads();
  #pragma unroll
  for (int j = 0; j < 32; j++){
    int flat = threadIdx.x + j*256;
    int ol = flat >> 7, kl = flat & 127;
    Bt[(size_t)(o0+ol)*KF + kf0 + kl] = tile[ol*130 + kl];
  }
}

// ---------------------------------------------------------------------------
// Phase A+B: one wave per query. Lane l owns feature channel c=l (0..63),
// accumulates weighted[q][k][c] for all q (4), k (15) -> 60 fp32 regs.
// Output: wsA bf16 row per query, flat index k*256 + q*64 + c.
// ---------------------------------------------------------------------------
__global__ __launch_bounds__(256) void build_weighted(
    const float* __restrict__ q_pts, const float* __restrict__ s_pts,
    const int*   __restrict__ inds,  const float* __restrict__ x,
    const float* __restrict__ q_lrf, const float* __restrict__ s_lrf,
    const float* __restrict__ kp,    const float* __restrict__ Wlrf,
    const float* __restrict__ blrf,  unsigned short* __restrict__ wsA,
    int n0)
{
  const int tid  = threadIdx.x;
  const int wid  = tid >> 6, lane = tid & 63;
  const int local = blockIdx.x*4 + wid;
  const int n = n0 + local;
  const bool vq = (n < NQPTS);

  __shared__ float s_slrf[4][40];
  __shared__ __align__(16) float s_alrf[4][144];
  __shared__ float s_feat[4][128];

  float qp0=0.f, qp1=0.f, qp2=0.f;
  if (vq){ qp0=q_pts[(size_t)n*3]; qp1=q_pts[(size_t)n*3+1]; qp2=q_pts[(size_t)n*3+2]; }
  int idxr = NSUP;
  if (vq && lane < NNB) idxr = inds[(size_t)n*NNB + lane];

  // roles for aligned_lrf stage: 3 rounds of 64 lanes cover v = q*36+u (144 vals)
  int sa[3], ja[3]; bool acta[3]; float qla[3][3];
  #pragma unroll
  for (int r = 0; r < 3; r++){
    int v = r*64 + lane;
    acta[r] = (v < 144);
    int vv = acta[r] ? v : 0;
    int q = vv/36, u = vv%36;
    sa[r] = u/9; int rem = u%9; int ia = rem/3; ja[r] = rem%3;
    #pragma unroll
    for (int k = 0; k < 3; k++)
      qla[r][k] = (vq && acta[r]) ? q_lrf[(size_t)n*36 + q*9 + k*3 + ia] : 0.f;
  }
  // roles for kernel-weight stage: lanes 0..59 -> (q,k)
  const int qw = (lane < 60) ? lane/15 : 0;
  const int kw = (lane < 60) ? lane%15 : 0;
  float qlw[9];
  #pragma unroll
  for (int t = 0; t < 9; t++) qlw[t] = vq ? q_lrf[(size_t)n*36 + qw*9 + t] : 0.f;
  const float kpx = kp[kw*3], kpy = kp[kw*3+1], kpz = kp[kw*3+2];

  const int cc = lane & 31;
  float wcol[36];
  #pragma unroll
  for (int u = 0; u < 36; u++) wcol[u] = Wlrf[u*32 + cc];
  const float blv = blrf[cc];

  float wacc[60];
  #pragma unroll
  for (int i = 0; i < 60; i++) wacc[i] = 0.f;

  for (int m = 0; m < NNB; m++){
    const int idx = __shfl(idxr, m);
    const bool val = (idx < NSUP);
    if (lane < 36) s_slrf[wid][lane] = val ? s_lrf[(size_t)idx*36 + lane] : 0.f;
    float d0,d1,d2;
    if (val){ d0 = s_pts[(size_t)idx*3]-qp0; d1 = s_pts[(size_t)idx*3+1]-qp1; d2 = s_pts[(size_t)idx*3+2]-qp2; }
    else    { d0 = 1e6f-qp0; d1 = 1e6f-qp1; d2 = 1e6f-qp2; }   // shadow point, same math as ref
    __syncthreads();

    // aligned_lrf[q][s,i,j] = sum_k ql[q,k,i] * slrf[s,k,j]
    #pragma unroll
    for (int r = 0; r < 3; r++){
      if (acta[r]){
        float acc = qla[r][0]*s_slrf[wid][sa[r]*9 + 0 + ja[r]]
                  + qla[r][1]*s_slrf[wid][sa[r]*9 + 3 + ja[r]]
                  + qla[r][2]*s_slrf[wid][sa[r]*9 + 6 + ja[r]];
        s_alrf[wid][r*64 + lane] = acc;
      }
    }
    // kernel-point influence: lanes 0..59 hold aw[q][k]
    float awv;
    {
      float a0 = d0*qlw[0] + d1*qlw[3] + d2*qlw[6];
      float a1 = d0*qlw[1] + d1*qlw[4] + d2*qlw[7];
      float a2 = d0*qlw[2] + d1*qlw[5] + d2*qlw[8];
      float s0 = a0-kpx, s1 = a1-kpy, s2 = a2-kpz;
      awv = fmaxf(0.f, 1.f - sqrtf(s0*s0+s1*s1+s2*s2)*EXTINV);
      if (lane >= 60) awv = 0.f;
    }
    __syncthreads();

    // lrf_features: two rounds, (q, cc) per lane, W_lrf column in registers
    #pragma unroll
    for (int r = 0; r < 2; r++){
      int q = r*2 + (lane>>5);
      const float* ap = &s_alrf[wid][q*36];
      float acc = blv;
      #pragma unroll
      for (int u4 = 0; u4 < 9; u4++){
        f32x4 av = *(const f32x4*)(ap + u4*4);
        acc = fmaf(av[0], wcol[u4*4+0], acc);
        acc = fmaf(av[1], wcol[u4*4+1], acc);
        acc = fmaf(av[2], wcol[u4*4+2], acc);
        acc = fmaf(av[3], wcol[u4*4+3], acc);
      }
      s_feat[wid][q*32 + cc] = val ? acc : 0.f;
    }
    __syncthreads();

    // neighbor feature for this lane's channel c
    float nx0, nx1, nx2, nx3;
    if (lane < 32){
      if (val){
        const float* xp = x + (size_t)idx*128 + lane;
        nx0 = xp[0]; nx1 = xp[32]; nx2 = xp[64]; nx3 = xp[96];
      } else { nx0=nx1=nx2=nx3=0.f; }
    } else {
      nx0 = s_feat[wid][ 0+cc]; nx1 = s_feat[wid][32+cc];
      nx2 = s_feat[wid][64+cc]; nx3 = s_feat[wid][96+cc];
    }
    // accumulate: wacc[q*15+k] += aw[q][k] * nx[q]   (aw broadcast via readlane)
    #pragma unroll
    for (int q = 0; q < 4; q++){
      float nq = (q==0)?nx0:(q==1)?nx1:(q==2)?nx2:nx3;
      #pragma unroll
      for (int k = 0; k < NKP; k++){
        float a = __int_as_float(__builtin_amdgcn_readlane(__float_as_int(awv), q*15+k));
        wacc[q*15+k] = fmaf(a, nq, wacc[q*15+k]);
      }
    }
  }

  const size_t base = (size_t)local * KF;
  #pragma unroll
  for (int q = 0; q < 4; q++)
    #pragma unroll
    for (int k = 0; k < NKP; k++)
      wsA[base + k*256 + q*64 + lane] = f2bf(wacc[q*15+k]);
}

// ---------------------------------------------------------------------------
// Phase C: out[n,o] = leaky(sum_kf A[n,kf]*Bt[o,kf] + bias[o])
// BM=128, BN=256(full), BK=32, 8 waves (2x4), mfma 16x16x32 bf16
// ---------------------------------------------------------------------------
__global__ __launch_bounds__(512) void gemm_out(
    const unsigned short* __restrict__ A,   // [padM][3840] bf16
    const unsigned short* __restrict__ Bt,  // [256][3840] bf16
    const float* __restrict__ bias,
    float* __restrict__ out, int n0)
{
  __shared__ __align__(16) unsigned short As[128*32];
  __shared__ __align__(16) unsigned short Bs[256*32];
  const int tid = threadIdx.x;
  const int wv = tid >> 6, lane = tid & 63;
  const int wr = wv >> 2, wc = wv & 3;
  const int m0 = blockIdx.x * 128;

  f32x4 acc[4][4];
  #pragma unroll
  for (int i = 0; i < 4; i++)
    #pragma unroll
    for (int j = 0; j < 4; j++){ f32x4 z = {0.f,0.f,0.f,0.f}; acc[i][j] = z; }

  const int ar = tid >> 2, ak = (tid & 3)*8;
  const unsigned short* aPtr  = A  + (size_t)(m0 + ar)*KF + ak;
  const unsigned short* bPtr0 = Bt + (size_t)(ar      )*KF + ak;
  const unsigned short* bPtr1 = Bt + (size_t)(128 + ar)*KF + ak;
  unsigned short* asw  = &As[ar*32 + ak];
  unsigned short* bsw0 = &Bs[(ar      )*32 + ak];
  unsigned short* bsw1 = &Bs[(128 + ar)*32 + ak];

  const unsigned short* afr = &As[(wr*64 + (lane&15))*32 + (lane>>4)*8];
  const unsigned short* bfr = &Bs[(wc*64 + (lane&15))*32 + (lane>>4)*8];

  for (int k0 = 0; k0 < KF; k0 += 32){
    u16x8 av  = *(const u16x8*)aPtr;
    u16x8 bv0 = *(const u16x8*)bPtr0;
    u16x8 bv1 = *(const u16x8*)bPtr1;
    aPtr += 32; bPtr0 += 32; bPtr1 += 32;
    __syncthreads();
    *(u16x8*)asw = av; *(u16x8*)bsw0 = bv0; *(u16x8*)bsw1 = bv1;
    __syncthreads();

    bf16x8 af[4], bf[4];
    #pragma unroll
    for (int mf = 0; mf < 4; mf++) af[mf] = *(const bf16x8*)(afr + mf*16*32);
    #pragma unroll
    for (int nf = 0; nf < 4; nf++) bf[nf] = *(const bf16x8*)(bfr + nf*16*32);
    #pragma unroll
    for (int mf = 0; mf < 4; mf++)
      #pragma unroll
      for (int nf = 0; nf < 4; nf++)
        acc[mf][nf] = __builtin_amdgcn_mfma_f32_16x16x32_bf16(af[mf], bf[nf], acc[mf][nf], 0, 0, 0);
  }

  #pragma unroll
  for (int mf = 0; mf < 4; mf++){
    #pragma unroll
    for (int nf = 0; nf < 4; nf++){
      #pragma unroll
      for (int r = 0; r < 4; r++){
        int row = wr*64 + mf*16 + (lane>>4)*4 + r;     // C/D: col=lane&15, row=(lane>>4)*4+reg
        int n_g = n0 + m0 + row;
        if (n_g < NQPTS){
          int o = wc*64 + nf*16 + (lane&15);
          float v = acc[mf][nf][r] + bias[o];
          out[(size_t)n_g*256 + o] = (v >= 0.f) ? v : 0.1f*v;
        }
      }
    }
  }
}

// ---------------------------------------------------------------------------
extern "C" void kernel_launch(void* const* d_in, const int* in_sizes, int n_in,
                              void* d_out, int out_size, void* d_ws, size_t ws_size,
                              hipStream_t stream)
{
  const float* q_pts = (const float*)d_in[0];
  const float* s_pts = (const float*)d_in[1];
  const int*   inds  = (const int*)  d_in[2];
  const float* x     = (const float*)d_in[3];
  const float* q_lrf = (const float*)d_in[4];
  const float* s_lrf = (const float*)d_in[5];
  const float* kp    = (const float*)d_in[6];
  const float* wts   = (const float*)d_in[7];
  const float* Wlrf  = (const float*)d_in[8];
  const float* blrf  = (const float*)d_in[9];
  const float* bias  = (const float*)d_in[10];
  float* out = (float*)d_out;

  const size_t BBYTES = (size_t)256 * KF * sizeof(unsigned short); // 1.97 MB
  unsigned short* wsB = (unsigned short*)d_ws;
  unsigned short* wsA = (unsigned short*)((char*)d_ws + BBYTES);

  size_t avail = (ws_size > BBYTES) ? (ws_size - BBYTES) : 0;
  long maxRows = (long)(avail / ((size_t)KF * sizeof(unsigned short)));
  long chunk = (maxRows / 128) * 128;
  if (chunk > 20096) chunk = 20096;
  if (chunk < 128)   chunk = 128;   // last-resort; assumes ws >= ~2.5 MB

  convert_wt<<<dim3(30, 4), 256, 0, stream>>>(wts, wsB);

  for (long n0 = 0; n0 < NQPTS; n0 += chunk){
    long rows = NQPTS - n0; if (rows > chunk) rows = chunk;
    long padM = ((rows + 127)/128)*128;
    build_weighted<<<(int)(padM/4), 256, 0, stream>>>(q_pts, s_pts, inds, x,
        q_lrf, s_lrf, kp, Wlrf, blrf, wsA, (int)n0);
    gemm_out<<<(int)(padM/128), 512, 0, stream>>>(wsA, wsB, bias, out, (int)n0);
  }
}

// Round 3
// 497.953 us; speedup vs baseline: 1.1888x; 1.1888x over previous
//
#include <hip/hip_runtime.h>

#define NQPTS 20000
#define NSUP  20000
#define NNB   30
#define NKP   15
#define KF    3840          // 15 * 256
#define EXTINV 20.0f        // 1 / 0.05

typedef __attribute__((ext_vector_type(4))) float f32x4;
typedef __attribute__((ext_vector_type(8))) short bf16x8;
typedef __attribute__((ext_vector_type(8))) unsigned short u16x8;

typedef __attribute__((address_space(1))) const unsigned int as1_u32;
typedef __attribute__((address_space(3))) unsigned int as3_u32;

__device__ __forceinline__ unsigned short f2bf(float f){
  unsigned int u = __float_as_uint(f);
  u = (u + 0x7FFFu + ((u >> 16) & 1u)) >> 16;   // RNE
  return (unsigned short)u;
}

__device__ __forceinline__ void gl_lds16(const unsigned short* g, unsigned short* l){
  __builtin_amdgcn_global_load_lds((as1_u32*)g, (as3_u32*)l, 16, 0, 0);
}

// swizzled offset (in shorts) for [row][32 m] bf16 LDS tiles, row stride 64B.
// XOR the 16B m-group with row&3 so column reads spread across banks.
__device__ __forceinline__ int swz_off(int row, int m){
  return row*32 + ((((m>>3) ^ (row&3)) << 3) | (m & 7));
}

// ---------------------------------------------------------------------------
// weights f32 [3840][256]  ->  Bt bf16 [256][3840]  (transposed via LDS)
// ---------------------------------------------------------------------------
__global__ __launch_bounds__(256) void convert_wt(const float* __restrict__ W,
                                                  unsigned short* __restrict__ Bt){
  __shared__ unsigned short tile[64*130];
  const int kf0 = blockIdx.x * 128, o0 = blockIdx.y * 64;
  const int to = threadIdx.x & 63, tk = threadIdx.x >> 6;
  #pragma unroll
  for (int i = 0; i < 32; i++){
    int kf = i*4 + tk;
    tile[to*130 + kf] = f2bf(W[(size_t)(kf0+kf)*256 + o0 + to]);
  }
  __syncthreads();
  #pragma unroll
  for (int j = 0; j < 32; j++){
    int flat = threadIdx.x + j*256;
    int ol = flat >> 7, kl = flat & 127;
    Bt[(size_t)(o0+ol)*KF + kf0 + kl] = tile[ol*130 + kl];
  }
}

// ---------------------------------------------------------------------------
// Phase A+B v2: ONE QUERY PER BLOCK (4 waves split the 30 neighbors).
// Per neighbor: geometry + aw -> AW LDS tile (bf16), lrf features + x gather
// -> NXT LDS tile (bf16, k-major). End: block-diag MFMA per wave (q=wid):
// weighted[k][q*64+c] = sum_m AW[q*16+k][m] * NXT[q*64+c][m].
// Only 2 __syncthreads per query; wave-internal LDS deps via lgkmcnt(0).
// ---------------------------------------------------------------------------
__global__ __launch_bounds__(256) void build_weighted_v2(
    const float* __restrict__ q_pts, const float* __restrict__ s_pts,
    const int*   __restrict__ inds,  const float* __restrict__ x,
    const float* __restrict__ q_lrf, const float* __restrict__ s_lrf,
    const float* __restrict__ kp,    const float* __restrict__ Wlrf,
    const float* __restrict__ blrf,  unsigned short* __restrict__ wsA,
    int n0)
{
  __shared__ __align__(16) unsigned short NXT[256*32];  // [c][m] swizzled, 16KB
  __shared__ __align__(16) unsigned short AWs[64*32];   // [q*16+k][m] swizzled, 4KB
  __shared__ float slrf[4][36];
  __shared__ __align__(16) float alrf[4][144];

  const int tid  = threadIdx.x;
  const int wid  = tid >> 6, lane = tid & 63;
  const int local = blockIdx.x;
  const int n = n0 + local;

  { // zero NXT + AWs (covers pad row k=15 and pad cols m=30,31)
    f32x4 z = {0.f,0.f,0.f,0.f};
    f32x4* p = (f32x4*)NXT;
    p[tid] = z; p[256+tid] = z; p[512+tid] = z; p[768+tid] = z;
    ((f32x4*)AWs)[tid] = z;
  }

  const float qp0 = q_pts[(size_t)n*3], qp1 = q_pts[(size_t)n*3+1], qp2 = q_pts[(size_t)n*3+2];
  int idxr = NSUP;
  if (lane < NNB) idxr = inds[(size_t)n*NNB + lane];

  // roles for aligned_lrf stage: 3 rounds of 64 lanes cover v = q*36+u (144 vals)
  int sa[3], ja[3]; bool acta[3]; float qla[3][3];
  #pragma unroll
  for (int r = 0; r < 3; r++){
    int v = r*64 + lane;
    acta[r] = (v < 144);
    int vv = acta[r] ? v : 0;
    int q = vv/36, u = vv%36;
    sa[r] = u/9; int rem = u%9; int ia = rem/3; ja[r] = rem%3;
    #pragma unroll
    for (int k = 0; k < 3; k++)
      qla[r][k] = acta[r] ? q_lrf[(size_t)n*36 + q*9 + k*3 + ia] : 0.f;
  }
  // roles for kernel-weight stage: lanes 0..59 -> (q,k)
  const int qw = (lane < 60) ? lane/15 : 0;
  const int kw = (lane < 60) ? lane%15 : 0;
  float qlw[9];
  #pragma unroll
  for (int t = 0; t < 9; t++) qlw[t] = q_lrf[(size_t)n*36 + qw*9 + t];
  const float kpx = kp[kw*3], kpy = kp[kw*3+1], kpz = kp[kw*3+2];

  const int cc = lane & 31;
  float wcol[36];
  #pragma unroll
  for (int u = 0; u < 36; u++) wcol[u] = Wlrf[u*32 + cc];
  const float blv = blrf[cc];

  __syncthreads();   // zero-init visible to all waves' writes/reads

  for (int m = wid; m < NNB; m += 4){
    const int idx = __shfl(idxr, m);
    const bool val = (idx < NSUP);
    if (lane < 36) slrf[wid][lane] = val ? s_lrf[(size_t)idx*36 + lane] : 0.f;
    float d0, d1, d2;
    if (val){ d0 = s_pts[(size_t)idx*3]-qp0; d1 = s_pts[(size_t)idx*3+1]-qp1; d2 = s_pts[(size_t)idx*3+2]-qp2; }
    else    { d0 = 1e6f-qp0; d1 = 1e6f-qp1; d2 = 1e6f-qp2; }   // shadow point, same math as ref

    // kernel-point influence (no LDS dep): lanes 0..59 hold aw[q][k]
    {
      float a0 = d0*qlw[0] + d1*qlw[3] + d2*qlw[6];
      float a1 = d0*qlw[1] + d1*qlw[4] + d2*qlw[7];
      float a2 = d0*qlw[2] + d1*qlw[5] + d2*qlw[8];
      float s0 = a0-kpx, s1 = a1-kpy, s2 = a2-kpz;
      float awv = fmaxf(0.f, 1.f - sqrtf(s0*s0+s1*s1+s2*s2)*EXTINV);
      if (lane < 60) AWs[swz_off(qw*16 + kw, m)] = f2bf(awv);
    }

    asm volatile("s_waitcnt lgkmcnt(0)" ::: "memory");  // slrf writes visible (wave-internal)

    // aligned_lrf[q][s,i,j] = sum_k ql[q,k,i] * slrf[s,k,j]
    #pragma unroll
    for (int r = 0; r < 3; r++){
      if (acta[r]){
        float acc = qla[r][0]*slrf[wid][sa[r]*9 + 0 + ja[r]]
                  + qla[r][1]*slrf[wid][sa[r]*9 + 3 + ja[r]]
                  + qla[r][2]*slrf[wid][sa[r]*9 + 6 + ja[r]];
        alrf[wid][r*64 + lane] = acc;
      }
    }

    asm volatile("s_waitcnt lgkmcnt(0)" ::: "memory");  // alrf writes visible (wave-internal)

    // lrf_features: two rounds, (q, cc) per lane -> NXT cols q*64+32+cc
    #pragma unroll
    for (int r = 0; r < 2; r++){
      int q = r*2 + (lane>>5);
      const float* ap = &alrf[wid][q*36];
      float acc = blv;
      #pragma unroll
      for (int u4 = 0; u4 < 9; u4++){
        f32x4 av = *(const f32x4*)(ap + u4*4);
        acc = fmaf(av[0], wcol[u4*4+0], acc);
        acc = fmaf(av[1], wcol[u4*4+1], acc);
        acc = fmaf(av[2], wcol[u4*4+2], acc);
        acc = fmaf(av[3], wcol[u4*4+3], acc);
      }
      NXT[swz_off(q*64 + 32 + cc, m)] = f2bf(val ? acc : 0.f);
    }

    // x features: lanes 0..31 -> NXT cols q*64+lane
    if (lane < 32){
      float v0, v1, v2, v3;
      if (val){
        const float* xp = x + (size_t)idx*128 + lane;
        v0 = xp[0]; v1 = xp[32]; v2 = xp[64]; v3 = xp[96];
      } else { v0 = v1 = v2 = v3 = 0.f; }
      NXT[swz_off(  0 + lane, m)] = f2bf(v0);
      NXT[swz_off( 64 + lane, m)] = f2bf(v1);
      NXT[swz_off(128 + lane, m)] = f2bf(v2);
      NXT[swz_off(192 + lane, m)] = f2bf(v3);
    }
  }

  __syncthreads();   // all waves' AW/NXT writes visible

  // final block-diag MFMA: wave wid handles q = wid
  const int fr = lane & 15, mg = lane >> 4;
  const int arow = wid*16 + fr;
  bf16x8 afrag = *(const bf16x8*)&AWs[arow*32 + ((mg ^ (arow&3)) << 3)];
  f32x4 accv[4];
  #pragma unroll
  for (int nf = 0; nf < 4; nf++){
    int col = wid*64 + nf*16 + fr;
    bf16x8 bfrag = *(const bf16x8*)&NXT[col*32 + ((mg ^ (col&3)) << 3)];
    f32x4 z = {0.f,0.f,0.f,0.f};
    accv[nf] = __builtin_amdgcn_mfma_f32_16x16x32_bf16(afrag, bfrag, z, 0, 0, 0);
  }
  const size_t base = (size_t)local * KF;
  #pragma unroll
  for (int nf = 0; nf < 4; nf++){
    #pragma unroll
    for (int r = 0; r < 4; r++){
      int k = mg*4 + r;                  // C/D: col=lane&15, row=(lane>>4)*4+r
      if (k < NKP)
        wsA[base + k*256 + wid*64 + nf*16 + fr] = f2bf(accv[nf][r]);
    }
  }
}

// ---------------------------------------------------------------------------
// Phase C v2: out[n,o] = leaky(sum_kf A[n,kf]*Bt[o,kf] + bias[o])
// BM=64, BN=256(full), BK=32, 4 waves (wave = 64x64), global_load_lds width16,
// 2-phase double-buffered pipeline. Grid = padM/64 (~314 blocks, ~4/CU).
// ---------------------------------------------------------------------------
__global__ __launch_bounds__(256) void gemm_out_v2(
    const unsigned short* __restrict__ A,   // [padM][3840] bf16
    const unsigned short* __restrict__ Bt,  // [256][3840] bf16
    const float* __restrict__ bias,
    float* __restrict__ out, int n0)
{
  __shared__ __align__(16) unsigned short As[2][64*32];    // 4KB each
  __shared__ __align__(16) unsigned short Bs[2][256*32];   // 16KB each
  const int tid = threadIdx.x, lane = tid & 63, wid = tid >> 6;
  const int m0 = blockIdx.x * 64;

  const unsigned short* aSrc = A  + (size_t)(m0 + (tid>>2))*KF + (tid&3)*8;
  const unsigned short* bSrc = Bt + (size_t)(tid>>2)*KF + (tid&3)*8;

  f32x4 acc[4][4];
  #pragma unroll
  for (int i = 0; i < 4; i++)
    #pragma unroll
    for (int j = 0; j < 4; j++){ f32x4 z = {0.f,0.f,0.f,0.f}; acc[i][j] = z; }

  const int afo = (lane&15)*32 + (lane>>4)*8;               // + mf*512
  const int bfo = (wid*64 + (lane&15))*32 + (lane>>4)*8;    // + nf*512

  #define STAGE(buf, k0)                                                     \
    do {                                                                     \
      gl_lds16(aSrc + (k0), &As[buf][tid*8]);                                \
      gl_lds16(bSrc + (size_t)0*64*KF + (k0), &Bs[buf][0*2048 + tid*8]);     \
      gl_lds16(bSrc + (size_t)1*64*KF + (k0), &Bs[buf][1*2048 + tid*8]);     \
      gl_lds16(bSrc + (size_t)2*64*KF + (k0), &Bs[buf][2*2048 + tid*8]);     \
      gl_lds16(bSrc + (size_t)3*64*KF + (k0), &Bs[buf][3*2048 + tid*8]);     \
    } while (0)

  STAGE(0, 0);
  asm volatile("s_waitcnt vmcnt(0)" ::: "memory");
  __syncthreads();

  int cur = 0;
  for (int t = 0; t < KF/32; ++t){
    if (t + 1 < KF/32) STAGE(cur^1, (t+1)*32);
    bf16x8 af[4], bf[4];
    #pragma unroll
    for (int mf = 0; mf < 4; mf++) af[mf] = *(const bf16x8*)&As[cur][afo + mf*512];
    #pragma unroll
    for (int nf = 0; nf < 4; nf++) bf[nf] = *(const bf16x8*)&Bs[cur][bfo + nf*512];
    #pragma unroll
    for (int mf = 0; mf < 4; mf++)
      #pragma unroll
      for (int nf = 0; nf < 4; nf++)
        acc[mf][nf] = __builtin_amdgcn_mfma_f32_16x16x32_bf16(af[mf], bf[nf], acc[mf][nf], 0, 0, 0);
    asm volatile("s_waitcnt vmcnt(0)" ::: "memory");
    __syncthreads();
    cur ^= 1;
  }
  #undef STAGE

  float bv[4];
  #pragma unroll
  for (int nf = 0; nf < 4; nf++) bv[nf] = bias[wid*64 + nf*16 + (lane&15)];
  #pragma unroll
  for (int mf = 0; mf < 4; mf++){
    #pragma unroll
    for (int nf = 0; nf < 4; nf++){
      #pragma unroll
      for (int r = 0; r < 4; r++){
        int row = mf*16 + (lane>>4)*4 + r;
        int n_g = n0 + m0 + row;
        if (n_g < NQPTS){
          int o = wid*64 + nf*16 + (lane&15);
          float v = acc[mf][nf][r] + bv[nf];
          out[(size_t)n_g*256 + o] = (v >= 0.f) ? v : 0.1f*v;
        }
      }
    }
  }
}

// ---------------------------------------------------------------------------
extern "C" void kernel_launch(void* const* d_in, const int* in_sizes, int n_in,
                              void* d_out, int out_size, void* d_ws, size_t ws_size,
                              hipStream_t stream)
{
  const float* q_pts = (const float*)d_in[0];
  const float* s_pts = (const float*)d_in[1];
  const int*   inds  = (const int*)  d_in[2];
  const float* x     = (const float*)d_in[3];
  const float* q_lrf = (const float*)d_in[4];
  const float* s_lrf = (const float*)d_in[5];
  const float* kp    = (const float*)d_in[6];
  const float* wts   = (const float*)d_in[7];
  const float* Wlrf  = (const float*)d_in[8];
  const float* blrf  = (const float*)d_in[9];
  const float* bias  = (const float*)d_in[10];
  float* out = (float*)d_out;

  const size_t BBYTES = (size_t)256 * KF * sizeof(unsigned short); // 1.97 MB
  unsigned short* wsB = (unsigned short*)d_ws;
  unsigned short* wsA = (unsigned short*)((char*)d_ws + BBYTES);

  size_t avail = (ws_size > BBYTES) ? (ws_size - BBYTES) : 0;
  long maxRows = (long)(avail / ((size_t)KF * sizeof(unsigned short)));
  long chunk = (maxRows / 128) * 128;
  if (chunk > 20096) chunk = 20096;
  if (chunk < 128)   chunk = 128;   // last-resort; assumes ws >= ~2.5 MB

  convert_wt<<<dim3(30, 4), 256, 0, stream>>>(wts, wsB);

  for (long n0 = 0; n0 < NQPTS; n0 += chunk){
    long rows = NQPTS - n0; if (rows > chunk) rows = chunk;
    long padM = ((rows + 63)/64)*64;
    build_weighted_v2<<<(int)rows, 256, 0, stream>>>(q_pts, s_pts, inds, x,
        q_lrf, s_lrf, kp, Wlrf, blrf, wsA, (int)n0);
    gemm_out_v2<<<(int)(padM/64), 256, 0, stream>>>(wsA, wsB, bias, out, (int)n0);
  }
}